// Round 10
// baseline (312.687 us; speedup 1.0000x reference)
//
#include <hip/hip_runtime.h>
#include <math.h>

typedef __bf16 bf16x8 __attribute__((ext_vector_type(8)));
typedef float  f32x4  __attribute__((ext_vector_type(4)));
typedef unsigned short u16x4 __attribute__((ext_vector_type(4)));

#define DEVI __device__ __forceinline__

static constexpr int NB  = 8;
static constexpr int NN  = 2048;
static constexpr int NF  = 128;
static constexpr int NC2 = 256;
static constexpr int NSK = 16;

static constexpr int OUT_X0  = 0;
static constexpr int OUT_A0  = NB * 128 * 128;
static constexpr int OUT_S0  = OUT_A0 + NB * 128 * 128;
static constexpr int OUT_LP  = OUT_S0 + NB * NN * 128;
static constexpr int OUT_ENT = OUT_LP + 1;

DEVI unsigned short f2b(float f) {                  // fp32 -> bf16 RNE
  unsigned int u = __builtin_bit_cast(unsigned int, f);
  u += 0x7fffu + ((u >> 16) & 1u);
  return (unsigned short)(u >> 16);
}
DEVI float b2f(unsigned short h) {
  unsigned int u = ((unsigned int)h) << 16;
  return __builtin_bit_cast(float, u);
}
DEVI void load_lds16(const void* g, void* l) {
  __builtin_amdgcn_global_load_lds(
      (const __attribute__((address_space(1))) void*)g,
      (__attribute__((address_space(3))) void*)l, 16, 0, 0);
}
DEVI int swz(int row) { return (row >> 1) & 3; }

// ---- LDS staging (slot row*4+c holds k-chunk c^swz(row); 2-way banks free) ----
DEVI void stage_a64(const unsigned short* src, int ld, unsigned short* dst,
                    int k0, int tid) {
  const int wave = tid >> 6;
  const int row = tid >> 2, c = tid & 3;
  load_lds16(src + (size_t)row * ld + k0 + ((c ^ swz(row)) << 3), dst + (wave << 9));
}
DEVI void stage_b128(const unsigned short* src, int ld, unsigned short* dst,
                     int k0, int tid) {
  const int wave = tid >> 6;
#pragma unroll
  for (int is = 0; is < 2; ++is) {
    const int row = is * 64 + (tid >> 2);
    const int c   = tid & 3;
    load_lds16(src + (size_t)row * ld + k0 + ((c ^ swz(row)) << 3),
               dst + ((is * 256 + wave * 64) << 3));
  }
}
DEVI void stage_b256(const unsigned short* src, int ld, unsigned short* dst,
                     int k0, int tid) {
  const int wave = tid >> 6;
#pragma unroll
  for (int is = 0; is < 4; ++is) {
    const int row = is * 64 + (tid >> 2);
    const int c   = tid & 3;
    load_lds16(src + (size_t)row * ld + k0 + ((c ^ swz(row)) << 3),
               dst + ((is * 256 + wave * 64) << 3));
  }
}

// ---- 64x128xK core: 4 waves, each 64 rows x 32 cols, acc[4][2] ----
DEVI void gemm_core64(const unsigned short* Aop, int lda,
                      const unsigned short* Bop, int ldb, int ksteps,
                      unsigned short* lA0, unsigned short* lA1,
                      unsigned short* lB0, unsigned short* lB1,
                      int tid, f32x4 (&acc)[4][2]) {
  const int lane = tid & 63, wave = tid >> 6;
  const int l15 = lane & 15;
  const int sx = (lane >> 4) ^ ((l15 >> 1) & 3);
#pragma unroll
  for (int i = 0; i < 4; ++i) {
    acc[i][0] = (f32x4){0.f, 0.f, 0.f, 0.f};
    acc[i][1] = (f32x4){0.f, 0.f, 0.f, 0.f};
  }
  stage_a64(Aop, lda, lA0, 0, tid);
  stage_b128(Bop, ldb, lB0, 0, tid);
  __syncthreads();
  for (int kt = 0; kt < ksteps; ++kt) {
    unsigned short* curA = (kt & 1) ? lA1 : lA0;
    unsigned short* curB = (kt & 1) ? lB1 : lB0;
    if (kt + 1 < ksteps) {
      const int k0 = (kt + 1) * 32;
      stage_a64(Aop, lda, (kt & 1) ? lA0 : lA1, k0, tid);
      stage_b128(Bop, ldb, (kt & 1) ? lB0 : lB1, k0, tid);
    }
    bf16x8 af[4], bg[2];
#pragma unroll
    for (int i = 0; i < 4; ++i)
      af[i] = *(const bf16x8*)(curA + (((i * 16 + l15) * 4 + sx) << 3));
#pragma unroll
    for (int j = 0; j < 2; ++j)
      bg[j] = *(const bf16x8*)(curB + (((wave * 32 + j * 16 + l15) * 4 + sx) << 3));
#pragma unroll
    for (int i = 0; i < 4; ++i)
#pragma unroll
      for (int j = 0; j < 2; ++j)
        acc[i][j] = __builtin_amdgcn_mfma_f32_16x16x32_bf16(af[i], bg[j],
                                                            acc[i][j], 0, 0, 0);
    __syncthreads();
  }
}

// ---- 128x128xK core (gemm_p) ----
DEVI void gemm_core128(const unsigned short* Aop, int lda,
                       const unsigned short* Bop, int ldb, int ksteps,
                       unsigned short* lA0, unsigned short* lA1,
                       unsigned short* lB0, unsigned short* lB1,
                       int tid, f32x4 (&acc)[4][4]) {
  const int lane = tid & 63, wave = tid >> 6;
  const int wr = wave >> 1, wc = wave & 1;
  const int l15 = lane & 15;
  const int sx = (lane >> 4) ^ ((l15 >> 1) & 3);
#pragma unroll
  for (int i = 0; i < 4; ++i)
#pragma unroll
    for (int j = 0; j < 4; ++j) acc[i][j] = (f32x4){0.f, 0.f, 0.f, 0.f};
  stage_b128(Aop, lda, lA0, 0, tid);
  stage_b128(Bop, ldb, lB0, 0, tid);
  __syncthreads();
  for (int kt = 0; kt < ksteps; ++kt) {
    unsigned short* curA = (kt & 1) ? lA1 : lA0;
    unsigned short* curB = (kt & 1) ? lB1 : lB0;
    if (kt + 1 < ksteps) {
      const int k0 = (kt + 1) * 32;
      stage_b128(Aop, lda, (kt & 1) ? lA0 : lA1, k0, tid);
      stage_b128(Bop, ldb, (kt & 1) ? lB0 : lB1, k0, tid);
    }
    bf16x8 af[4], bg[4];
#pragma unroll
    for (int i = 0; i < 4; ++i)
      af[i] = *(const bf16x8*)(curA + (((wr * 64 + i * 16 + l15) * 4 + sx) << 3));
#pragma unroll
    for (int j = 0; j < 4; ++j)
      bg[j] = *(const bf16x8*)(curB + (((wc * 64 + j * 16 + l15) * 4 + sx) << 3));
#pragma unroll
    for (int i = 0; i < 4; ++i)
#pragma unroll
      for (int j = 0; j < 4; ++j)
        acc[i][j] = __builtin_amdgcn_mfma_f32_16x16x32_bf16(af[i], bg[j],
                                                            acc[i][j], 0, 0, 0);
    __syncthreads();
  }
}

// ---- prep: A->bf16+rowsum, X->bf16, W->WT (high occupancy) ----
__global__ __launch_bounds__(256) void k_prep(const float* __restrict__ A,
                                              const float* __restrict__ X,
                                              const float* __restrict__ Wemb,
                                              const float* __restrict__ Wpool,
                                              unsigned short* __restrict__ AB,
                                              unsigned short* __restrict__ XB,
                                              unsigned short* __restrict__ WT,
                                              float* __restrict__ dvec,
                                              float* __restrict__ rsum) {
  const int blk = blockIdx.x, tid = threadIdx.x;
  if (blk < 4096) {
    const int row = blk * 4 + (tid >> 6);
    const int lane = tid & 63;
    const f32x4* src = (const f32x4*)(A + ((size_t)row << 11));
    u16x4* dst = (u16x4*)(AB + ((size_t)row << 11));
    float s = 0.f;
#pragma unroll
    for (int it = 0; it < 8; ++it) {
      f32x4 v = src[it * 64 + lane];
      s += v[0] + v[1] + v[2] + v[3];
      u16x4 o;
      o[0] = f2b(v[0]); o[1] = f2b(v[1]); o[2] = f2b(v[2]); o[3] = f2b(v[3]);
      dst[it * 64 + lane] = o;
    }
#pragma unroll
    for (int o2 = 32; o2; o2 >>= 1) s += __shfl_down(s, o2);
    if (lane == 0) { dvec[row] = rsqrtf(s + 1.f); rsum[row] = s; }
  } else if (blk < 4608) {
    const int i0 = (blk - 4096) * 1024 + tid;
    const f32x4* src = (const f32x4*)X;
    u16x4* dst = (u16x4*)XB;
#pragma unroll
    for (int it = 0; it < 4; ++it) {
      f32x4 v = src[i0 + it * 256];
      u16x4 o;
      o[0] = f2b(v[0]); o[1] = f2b(v[1]); o[2] = f2b(v[2]); o[3] = f2b(v[3]);
      dst[i0 + it * 256] = o;
    }
  } else {
    const int e = (blk - 4608) * 256 + tid;
    const int c = e >> 4, f0 = (e & 15) * 8;
    const float* W = (c < 128) ? Wemb : Wpool;
    const int cc = c & 127;
#pragma unroll
    for (int q = 0; q < 8; ++q)
      WT[c * 128 + f0 + q] = f2b(W[(f0 + q) * 128 + cc]);
  }
}

// ---- VT = d * (X @ Wcat) (transposed store) ----
__global__ __launch_bounds__(256) void k_gemm_xw(const unsigned short* __restrict__ XB,
                                                 const unsigned short* __restrict__ WT,
                                                 const float* __restrict__ dvec,
                                                 unsigned short* __restrict__ VT) {
  __shared__ unsigned short lA[2][2048], lB[2][4096];
  const int mt = blockIdx.x, ct = blockIdx.y, tid = threadIdx.x;
  f32x4 acc[4][2];
  gemm_core64(XB + mt * 64 * NF, NF, WT + ct * 128 * NF, NF, NF / 32,
              lA[0], lA[1], lB[0], lB[1], tid, acc);
  const int lane = tid & 63, wave = tid >> 6;
  const int l15 = lane & 15, l4 = (lane >> 4) * 4;
#pragma unroll
  for (int i = 0; i < 4; ++i) {
    const int gr0 = mt * 64 + i * 16 + l4;
    const int b = gr0 >> 11, n0 = gr0 & 2047;
    const f32x4 dv = *(const f32x4*)(dvec + gr0);
#pragma unroll
    for (int j = 0; j < 2; ++j) {
      const int gc = ct * 128 + wave * 32 + j * 16 + l15;
      u16x4 pk;
#pragma unroll
      for (int r = 0; r < 4; ++r) pk[r] = f2b(acc[i][j][r] * dv[r]);
      *(u16x4*)(VT + (((size_t)(b * NC2 + gc)) << 11) + n0) = pk;
    }
  }
}

// ---- U = (A@V + V)*d, BM=64 BN=256 (A read ONCE): Z_T (cols 0..127) +
//      fused softmax S + S_T + entropy (cols 128..255). XCD-pinned b = pid&7.
__global__ __launch_bounds__(256) void k_gemm_nv(const unsigned short* __restrict__ AB,
                                                 const unsigned short* __restrict__ VT,
                                                 const float* __restrict__ dvec,
                                                 unsigned short* __restrict__ YT,
                                                 float* __restrict__ out,
                                                 float* __restrict__ entv) {
  __shared__ __align__(16) unsigned short sm16[20480];   // A 2x4KB | B 2x16KB
  float* smf = (float*)sm16;
  const int pid = blockIdx.x, tid = threadIdx.x;
  const int b = pid & 7, mt = pid >> 3;                  // 32 mt x 8 b = 256
  const unsigned short* Aop = AB + ((size_t)b << 22) + (size_t)mt * 64 * NN;
  const unsigned short* Bop = VT + (((size_t)(b * NC2)) << 11);
  unsigned short* lA0 = sm16, *lA1 = sm16 + 2048;
  unsigned short* lB0 = sm16 + 4096, *lB1 = sm16 + 12288;
  const int lane = tid & 63, wave = tid >> 6;
  const int l15 = lane & 15, l4g = lane >> 4, l4 = l4g * 4;
  const int sx = (lane >> 4) ^ ((l15 >> 1) & 3);
  f32x4 acc[4][4];
#pragma unroll
  for (int i = 0; i < 4; ++i)
#pragma unroll
    for (int j = 0; j < 4; ++j) acc[i][j] = (f32x4){0.f, 0.f, 0.f, 0.f};
  stage_a64(Aop, NN, lA0, 0, tid);
  stage_b256(Bop, NN, lB0, 0, tid);
  __syncthreads();
  for (int kt = 0; kt < 64; ++kt) {
    unsigned short* curA = (kt & 1) ? lA1 : lA0;
    unsigned short* curB = (kt & 1) ? lB1 : lB0;
    if (kt + 1 < 64) {
      const int k0 = (kt + 1) * 32;
      stage_a64(Aop, NN, (kt & 1) ? lA0 : lA1, k0, tid);
      stage_b256(Bop, NN, (kt & 1) ? lB0 : lB1, k0, tid);
    }
    bf16x8 af[4], bg[4];
#pragma unroll
    for (int i = 0; i < 4; ++i)
      af[i] = *(const bf16x8*)(curA + (((i * 16 + l15) * 4 + sx) << 3));
#pragma unroll
    for (int j = 0; j < 4; ++j) {
      const int row = (j < 2) ? (wave * 32 + j * 16 + l15)
                              : (128 + wave * 32 + (j - 2) * 16 + l15);
      bg[j] = *(const bf16x8*)(curB + ((row * 4 + sx) << 3));
    }
#pragma unroll
    for (int i = 0; i < 4; ++i)
#pragma unroll
      for (int j = 0; j < 4; ++j)
        acc[i][j] = __builtin_amdgcn_mfma_f32_16x16x32_bf16(af[i], bg[j],
                                                            acc[i][j], 0, 0, 0);
    __syncthreads();
  }
  // V-add + d-scale
  f32x4 dv[4];
#pragma unroll
  for (int i = 0; i < 4; ++i)
    dv[i] = *(const f32x4*)(dvec + (b << 11) + mt * 64 + i * 16 + l4);
#pragma unroll
  for (int i = 0; i < 4; ++i) {
    const int n0 = mt * 64 + i * 16 + l4;
#pragma unroll
    for (int j = 0; j < 4; ++j) {
      const int vrow = (j < 2) ? (wave * 32 + j * 16 + l15)
                               : (128 + wave * 32 + (j - 2) * 16 + l15);
      const u16x4 vv = *(const u16x4*)(VT + (((size_t)(b * NC2 + vrow)) << 11) + n0);
#pragma unroll
      for (int r = 0; r < 4; ++r)
        acc[i][j][r] = (acc[i][j][r] + b2f(vv[r])) * dv[i][r];
    }
  }
  // Z store (j=0,1 -> YT rows 0..127)
#pragma unroll
  for (int i = 0; i < 4; ++i) {
    const int n0 = mt * 64 + i * 16 + l4;
#pragma unroll
    for (int j = 0; j < 2; ++j) {
      const int c = wave * 32 + j * 16 + l15;
      u16x4 pk;
#pragma unroll
      for (int r = 0; r < 4; ++r) pk[r] = f2b(acc[i][j][r]);
      *(u16x4*)(YT + (((size_t)(b * 384 + c)) << 11) + n0) = pk;
    }
  }
  // fused softmax over j=2,3 (S cols 0..127)
  float* mbuf = smf;                                // [4][64]
  float* sbuf = smf + 256;
  float* tbuf = smf + 512;
  float* ebuf = smf + 768;
  float rm[4][4], rs[4][4], rt[4][4];
#pragma unroll
  for (int i = 0; i < 4; ++i)
#pragma unroll
    for (int r = 0; r < 4; ++r) {
      float m = fmaxf(acc[i][2][r], acc[i][3][r]);
#pragma unroll
      for (int off = 1; off < 16; off <<= 1) m = fmaxf(m, __shfl_xor(m, off));
      if (l15 == 0) mbuf[wave * 64 + i * 16 + l4 + r] = m;
    }
  __syncthreads();
#pragma unroll
  for (int i = 0; i < 4; ++i)
#pragma unroll
    for (int r = 0; r < 4; ++r) {
      const int row = i * 16 + l4 + r;
      rm[i][r] = fmaxf(fmaxf(mbuf[row], mbuf[64 + row]),
                       fmaxf(mbuf[128 + row], mbuf[192 + row]));
      rs[i][r] = 0.f; rt[i][r] = 0.f;
    }
#pragma unroll
  for (int i = 0; i < 4; ++i)
#pragma unroll
    for (int j = 2; j < 4; ++j)
#pragma unroll
      for (int r = 0; r < 4; ++r) {
        const float xm = acc[i][j][r] - rm[i][r];
        const float e = __expf(xm);
        acc[i][j][r] = e;
        rs[i][r] += e;
        rt[i][r] += xm * e;
      }
#pragma unroll
  for (int i = 0; i < 4; ++i)
#pragma unroll
    for (int r = 0; r < 4; ++r) {
      float s = rs[i][r], t = rt[i][r];
#pragma unroll
      for (int off = 1; off < 16; off <<= 1) {
        s += __shfl_xor(s, off); t += __shfl_xor(t, off);
      }
      if (l15 == 0) {
        sbuf[wave * 64 + i * 16 + l4 + r] = s;
        tbuf[wave * 64 + i * 16 + l4 + r] = t;
      }
    }
  __syncthreads();
  float ent = 0.f;
#pragma unroll
  for (int i = 0; i < 4; ++i)
#pragma unroll
    for (int r = 0; r < 4; ++r) {
      const int row = i * 16 + l4 + r;
      const float s = sbuf[row] + sbuf[64 + row] + sbuf[128 + row] + sbuf[192 + row];
      const float t = tbuf[row] + tbuf[64 + row] + tbuf[128 + row] + tbuf[192 + row];
      const float inv = 1.f / s;
      rs[i][r] = inv;
      ent += __logf(s) - t * inv;
    }
#pragma unroll
  for (int i = 0; i < 4; ++i) {
    const int n0 = mt * 64 + i * 16 + l4;
#pragma unroll
    for (int j = 2; j < 4; ++j) {
      const int cs = wave * 32 + (j - 2) * 16 + l15;
      u16x4 pk;
#pragma unroll
      for (int r = 0; r < 4; ++r) {
        const float sv = acc[i][j][r] * rs[i][r];
        pk[r] = f2b(sv);
        out[OUT_S0 + (((size_t)((b << 11) + n0 + r)) << 7) + cs] = sv;
      }
      *(u16x4*)(YT + (((size_t)(b * 384 + 256 + cs)) << 11) + n0) = pk;
    }
  }
  if (wave == 0 && l15 == 0) ebuf[l4g] = ent;
  __syncthreads();
  if (tid == 0)
    entv[b * 32 + mt] = ebuf[0] + ebuf[1] + ebuf[2] + ebuf[3];
}

// ---- AS_T = (A @ S)^T -> YT rows 128..255 (XCD-pinned: batch = pid&7) ----
__global__ __launch_bounds__(256) void k_gemm_as(const unsigned short* __restrict__ AB,
                                                 unsigned short* __restrict__ YT) {
  __shared__ unsigned short lA[2][2048], lB[2][4096];
  const int pid = blockIdx.x, tid = threadIdx.x;
  const int b = pid & 7, mt = pid >> 3;
  f32x4 acc[4][2];
  gemm_core64(AB + ((size_t)b << 22) + (size_t)mt * 64 * NN, NN,
              YT + (((size_t)(b * 384 + 256)) << 11), NN, NN / 32,
              lA[0], lA[1], lB[0], lB[1], tid, acc);
  const int lane = tid & 63, wave = tid >> 6;
  const int l15 = lane & 15, l4 = (lane >> 4) * 4;
#pragma unroll
  for (int i = 0; i < 4; ++i) {
    const int n0 = mt * 64 + i * 16 + l4;
#pragma unroll
    for (int j = 0; j < 2; ++j) {
      const int c = wave * 32 + j * 16 + l15;
      u16x4 pk;
#pragma unroll
      for (int r = 0; r < 4; ++r) pk[r] = f2b(acc[i][j][r]);
      *(u16x4*)(YT + (((size_t)(b * 384 + 128 + c)) << 11) + n0) = pk;
    }
  }
}

// ---- P = S^T @ [Z|AS|S], split-K=16 -> fp32 partials (XCD-pinned by batch) ----
__global__ __launch_bounds__(256) void k_gemm_p(const unsigned short* __restrict__ YT,
                                                float* __restrict__ Pp) {
  __shared__ unsigned short lA[2][4096], lB[2][4096];
  const int pid = blockIdx.x, tid = threadIdx.x;
  const int b = pid & 7, slot = pid >> 3;          // slot 0..47
  const int ct = slot % 3, sk = slot / 3;
  f32x4 acc[4][4];
  gemm_core128(YT + (((size_t)(b * 384 + 256)) << 11) + sk * 128, NN,
               YT + (((size_t)(b * 384 + ct * 128)) << 11) + sk * 128, NN, 4,
               lA[0], lA[1], lB[0], lB[1], tid, acc);
  const int lane = tid & 63, wave = tid >> 6;
  const int wr = wave >> 1, wc = wave & 1, l15 = lane & 15, l4 = (lane >> 4) * 4;
  float* dst = Pp + ((size_t)(sk * NB + b)) * 128 * 384;
#pragma unroll
  for (int i = 0; i < 4; ++i) {
    const int p0 = wr * 64 + i * 16 + l4;
#pragma unroll
    for (int j = 0; j < 4; ++j) {
      const int gc = ct * 128 + wc * 64 + j * 16 + l15;
#pragma unroll
      for (int r = 0; r < 4; ++r) dst[(p0 + r) * 384 + gc] = acc[i][j][r];
    }
  }
}

// ---- reduce split-K; write X_pooled/A_pooled; tr/g2 partials ----
__global__ __launch_bounds__(256) void k_reduce_p(const float* __restrict__ Pp,
                                                  float* __restrict__ trp,
                                                  float* __restrict__ g2p,
                                                  float* __restrict__ out) {
  const int chunk = blockIdx.x, b = blockIdx.y, tid = threadIdx.x;
  const int e = chunk * 256 + tid;
  const int p = e / 384, c = e - p * 384;
  float s = 0.f;
#pragma unroll
  for (int sk = 0; sk < NSK; ++sk)
    s += Pp[((size_t)(sk * NB + b)) * (128 * 384) + e];
  float tr = 0.f, g2 = 0.f;
  if (c < 128) {
    out[OUT_X0 + ((size_t)(b * 128 + p)) * 128 + c] = s;
  } else if (c < 256) {
    out[OUT_A0 + ((size_t)(b * 128 + p)) * 128 + (c - 128)] = s;
    if (c - 128 == p) tr = s;
  } else {
    g2 = s * s;
  }
  __shared__ float rb[512];
  rb[tid] = tr; rb[256 + tid] = g2;
  __syncthreads();
  for (int o = 128; o; o >>= 1) {
    if (tid < o) { rb[tid] += rb[tid + o]; rb[256 + tid] += rb[256 + tid + o]; }
    __syncthreads();
  }
  if (tid == 0) { trp[b * 192 + chunk] = rb[0]; g2p[b * 192 + chunk] = rb[256]; }
}

__global__ __launch_bounds__(256) void k_lp(const float* __restrict__ rsum,
                                            const float* __restrict__ trp,
                                            const float* __restrict__ g2p,
                                            float* __restrict__ lpv) {
  const int b = blockIdx.x, tid = threadIdx.x;
  float nz = 0.f;
#pragma unroll
  for (int i = 0; i < 8; ++i) nz += rsum[(b << 11) + i * 256 + tid];
  float tr = (tid < 192) ? trp[b * 192 + tid] : 0.f;
  float g2 = (tid < 192) ? g2p[b * 192 + tid] : 0.f;
  __shared__ float rb[768];
  rb[tid] = nz; rb[256 + tid] = tr; rb[512 + tid] = g2;
  __syncthreads();
  for (int o = 128; o; o >>= 1) {
    if (tid < o) {
      rb[tid] += rb[tid + o];
      rb[256 + tid] += rb[256 + tid + o];
      rb[512 + tid] += rb[512 + tid + o];
    }
    __syncthreads();
  }
  if (tid == 0)
    lpv[b] = sqrtf(fmaxf(rb[0] - 2.f * rb[256] + rb[512], 0.f));
}

__global__ __launch_bounds__(256) void k_losses(const float* __restrict__ entv,
                                                const float* __restrict__ lpv,
                                                float* __restrict__ out) {
  const int tid = threadIdx.x;
  __shared__ float rb[256];
  rb[tid] = entv[tid];
  __syncthreads();
  for (int o = 128; o; o >>= 1) {
    if (tid < o) rb[tid] += rb[tid + o];
    __syncthreads();
  }
  if (tid == 0) {
    float lp = 0.f;
#pragma unroll
    for (int b = 0; b < 8; ++b) lp += lpv[b];
    out[OUT_LP] = 0.125f * lp;
    out[OUT_ENT] = rb[0] * (1.f / (NB * NN));
  }
}

extern "C" void kernel_launch(void* const* d_in, const int* in_sizes, int n_in,
                              void* d_out, int out_size, void* d_ws, size_t ws_size,
                              hipStream_t stream) {
  const float* X     = (const float*)d_in[0];
  const float* A     = (const float*)d_in[1];
  const float* Wemb  = (const float*)d_in[2];
  const float* Wpool = (const float*)d_in[3];
  float* out = (float*)d_out;

  char* ws = (char*)d_ws;
  size_t o = 0;
  unsigned short* AB = (unsigned short*)(ws + o); o += (size_t)NB * NN * NN * 2;
  unsigned short* XB = (unsigned short*)(ws + o); o += (size_t)NB * NN * NF * 2;
  unsigned short* WT = (unsigned short*)(ws + o); o += (size_t)NC2 * NF * 2;
  unsigned short* VT = (unsigned short*)(ws + o); o += (size_t)NB * NC2 * NN * 2;
  unsigned short* YT = (unsigned short*)(ws + o); o += (size_t)NB * 384 * NN * 2;
  float* Pp  = (float*)(ws + o); o += (size_t)NSK * NB * 128 * 384 * 4;
  float* dvec = (float*)(ws + o); o += (size_t)NB * NN * 4;
  float* rsum = (float*)(ws + o); o += (size_t)NB * NN * 4;
  float* trp  = (float*)(ws + o); o += (size_t)NB * 192 * 4;
  float* g2p  = (float*)(ws + o); o += (size_t)NB * 192 * 4;
  float* entv = (float*)(ws + o); o += 256 * 4;
  float* lpv  = (float*)(ws + o); o += NB * 4;

  k_prep    <<<dim3(4624), 256, 0, stream>>>(A, X, Wemb, Wpool, AB, XB, WT, dvec, rsum);
  k_gemm_xw <<<dim3(NB * NN / 64, 2), 256, 0, stream>>>(XB, WT, dvec, VT);
  k_gemm_nv <<<dim3(256), 256, 0, stream>>>(AB, VT, dvec, YT, out, entv);
  k_gemm_as <<<dim3(256), 256, 0, stream>>>(AB, YT);
  k_gemm_p  <<<dim3(384), 256, 0, stream>>>(YT, Pp);
  k_reduce_p<<<dim3(192, NB), 256, 0, stream>>>(Pp, trp, g2p, out);
  k_lp      <<<dim3(NB), 256, 0, stream>>>(rsum, trp, g2p, lpv);
  k_losses  <<<1, 256, 0, stream>>>(entv, lpv, out);
}

// Round 11
// 300.569 us; speedup vs baseline: 1.0403x; 1.0403x over previous
//
#include <hip/hip_runtime.h>
#include <math.h>

typedef __bf16 bf16x8 __attribute__((ext_vector_type(8)));
typedef float  f32x4  __attribute__((ext_vector_type(4)));
typedef unsigned short u16x4 __attribute__((ext_vector_type(4)));

#define DEVI __device__ __forceinline__

static constexpr int NB  = 8;
static constexpr int NN  = 2048;
static constexpr int NF  = 128;
static constexpr int NC2 = 256;
static constexpr int NSK = 16;

static constexpr int OUT_X0  = 0;
static constexpr int OUT_A0  = NB * 128 * 128;
static constexpr int OUT_S0  = OUT_A0 + NB * 128 * 128;
static constexpr int OUT_LP  = OUT_S0 + NB * NN * 128;
static constexpr int OUT_ENT = OUT_LP + 1;

DEVI unsigned short f2b(float f) {                  // fp32 -> bf16 RNE
  unsigned int u = __builtin_bit_cast(unsigned int, f);
  u += 0x7fffu + ((u >> 16) & 1u);
  return (unsigned short)(u >> 16);
}
DEVI float b2f(unsigned short h) {
  unsigned int u = ((unsigned int)h) << 16;
  return __builtin_bit_cast(float, u);
}
DEVI void load_lds16(const void* g, void* l) {
  __builtin_amdgcn_global_load_lds(
      (const __attribute__((address_space(1))) void*)g,
      (__attribute__((address_space(3))) void*)l, 16, 0, 0);
}
DEVI int swz(int row) { return (row >> 1) & 3; }

// ---- LDS staging (slot row*4+c holds k-chunk c^swz(row); 2-way banks free) ----
DEVI void stage_a64(const unsigned short* src, int ld, unsigned short* dst,
                    int k0, int tid) {
  const int wave = tid >> 6;
  const int row = tid >> 2, c = tid & 3;
  load_lds16(src + (size_t)row * ld + k0 + ((c ^ swz(row)) << 3), dst + (wave << 9));
}
DEVI void stage_b128(const unsigned short* src, int ld, unsigned short* dst,
                     int k0, int tid) {
  const int wave = tid >> 6;
#pragma unroll
  for (int is = 0; is < 2; ++is) {
    const int row = is * 64 + (tid >> 2);
    const int c   = tid & 3;
    load_lds16(src + (size_t)row * ld + k0 + ((c ^ swz(row)) << 3),
               dst + ((is * 256 + wave * 64) << 3));
  }
}

// ---- 64x128xK core: 4 waves, each 64 rows x 32 cols, acc[4][2] ----
DEVI void gemm_core64(const unsigned short* Aop, int lda,
                      const unsigned short* Bop, int ldb, int ksteps,
                      unsigned short* lA0, unsigned short* lA1,
                      unsigned short* lB0, unsigned short* lB1,
                      int tid, f32x4 (&acc)[4][2]) {
  const int lane = tid & 63, wave = tid >> 6;
  const int l15 = lane & 15;
  const int sx = (lane >> 4) ^ ((l15 >> 1) & 3);
#pragma unroll
  for (int i = 0; i < 4; ++i) {
    acc[i][0] = (f32x4){0.f, 0.f, 0.f, 0.f};
    acc[i][1] = (f32x4){0.f, 0.f, 0.f, 0.f};
  }
  stage_a64(Aop, lda, lA0, 0, tid);
  stage_b128(Bop, ldb, lB0, 0, tid);
  __syncthreads();
  for (int kt = 0; kt < ksteps; ++kt) {
    unsigned short* curA = (kt & 1) ? lA1 : lA0;
    unsigned short* curB = (kt & 1) ? lB1 : lB0;
    if (kt + 1 < ksteps) {
      const int k0 = (kt + 1) * 32;
      stage_a64(Aop, lda, (kt & 1) ? lA0 : lA1, k0, tid);
      stage_b128(Bop, ldb, (kt & 1) ? lB0 : lB1, k0, tid);
    }
    bf16x8 af[4], bg[2];
#pragma unroll
    for (int i = 0; i < 4; ++i)
      af[i] = *(const bf16x8*)(curA + (((i * 16 + l15) * 4 + sx) << 3));
#pragma unroll
    for (int j = 0; j < 2; ++j)
      bg[j] = *(const bf16x8*)(curB + (((wave * 32 + j * 16 + l15) * 4 + sx) << 3));
#pragma unroll
    for (int i = 0; i < 4; ++i)
#pragma unroll
      for (int j = 0; j < 2; ++j)
        acc[i][j] = __builtin_amdgcn_mfma_f32_16x16x32_bf16(af[i], bg[j],
                                                            acc[i][j], 0, 0, 0);
    __syncthreads();
  }
}

// ---- 128x128xK core (gemm_p) ----
DEVI void gemm_core128(const unsigned short* Aop, int lda,
                       const unsigned short* Bop, int ldb, int ksteps,
                       unsigned short* lA0, unsigned short* lA1,
                       unsigned short* lB0, unsigned short* lB1,
                       int tid, f32x4 (&acc)[4][4]) {
  const int lane = tid & 63, wave = tid >> 6;
  const int wr = wave >> 1, wc = wave & 1;
  const int l15 = lane & 15;
  const int sx = (lane >> 4) ^ ((l15 >> 1) & 3);
#pragma unroll
  for (int i = 0; i < 4; ++i)
#pragma unroll
    for (int j = 0; j < 4; ++j) acc[i][j] = (f32x4){0.f, 0.f, 0.f, 0.f};
  stage_b128(Aop, lda, lA0, 0, tid);
  stage_b128(Bop, ldb, lB0, 0, tid);
  __syncthreads();
  for (int kt = 0; kt < ksteps; ++kt) {
    unsigned short* curA = (kt & 1) ? lA1 : lA0;
    unsigned short* curB = (kt & 1) ? lB1 : lB0;
    if (kt + 1 < ksteps) {
      const int k0 = (kt + 1) * 32;
      stage_b128(Aop, lda, (kt & 1) ? lA0 : lA1, k0, tid);
      stage_b128(Bop, ldb, (kt & 1) ? lB0 : lB1, k0, tid);
    }
    bf16x8 af[4], bg[4];
#pragma unroll
    for (int i = 0; i < 4; ++i)
      af[i] = *(const bf16x8*)(curA + (((wr * 64 + i * 16 + l15) * 4 + sx) << 3));
#pragma unroll
    for (int j = 0; j < 4; ++j)
      bg[j] = *(const bf16x8*)(curB + (((wc * 64 + j * 16 + l15) * 4 + sx) << 3));
#pragma unroll
    for (int i = 0; i < 4; ++i)
#pragma unroll
      for (int j = 0; j < 4; ++j)
        acc[i][j] = __builtin_amdgcn_mfma_f32_16x16x32_bf16(af[i], bg[j],
                                                            acc[i][j], 0, 0, 0);
    __syncthreads();
  }
}

// ---- prep: A->bf16+rowsum, X->bf16, W->WT (high occupancy) ----
__global__ __launch_bounds__(256) void k_prep(const float* __restrict__ A,
                                              const float* __restrict__ X,
                                              const float* __restrict__ Wemb,
                                              const float* __restrict__ Wpool,
                                              unsigned short* __restrict__ AB,
                                              unsigned short* __restrict__ XB,
                                              unsigned short* __restrict__ WT,
                                              float* __restrict__ dvec,
                                              float* __restrict__ rsum) {
  const int blk = blockIdx.x, tid = threadIdx.x;
  if (blk < 4096) {
    const int row = blk * 4 + (tid >> 6);
    const int lane = tid & 63;
    const f32x4* src = (const f32x4*)(A + ((size_t)row << 11));
    u16x4* dst = (u16x4*)(AB + ((size_t)row << 11));
    float s = 0.f;
#pragma unroll
    for (int it = 0; it < 8; ++it) {
      f32x4 v = src[it * 64 + lane];
      s += v[0] + v[1] + v[2] + v[3];
      u16x4 o;
      o[0] = f2b(v[0]); o[1] = f2b(v[1]); o[2] = f2b(v[2]); o[3] = f2b(v[3]);
      dst[it * 64 + lane] = o;
    }
#pragma unroll
    for (int o2 = 32; o2; o2 >>= 1) s += __shfl_down(s, o2);
    if (lane == 0) { dvec[row] = rsqrtf(s + 1.f); rsum[row] = s; }
  } else if (blk < 4608) {
    const int i0 = (blk - 4096) * 1024 + tid;
    const f32x4* src = (const f32x4*)X;
    u16x4* dst = (u16x4*)XB;
#pragma unroll
    for (int it = 0; it < 4; ++it) {
      f32x4 v = src[i0 + it * 256];
      u16x4 o;
      o[0] = f2b(v[0]); o[1] = f2b(v[1]); o[2] = f2b(v[2]); o[3] = f2b(v[3]);
      dst[i0 + it * 256] = o;
    }
  } else {
    const int e = (blk - 4608) * 256 + tid;
    const int c = e >> 4, f0 = (e & 15) * 8;
    const float* W = (c < 128) ? Wemb : Wpool;
    const int cc = c & 127;
#pragma unroll
    for (int q = 0; q < 8; ++q)
      WT[c * 128 + f0 + q] = f2b(W[(f0 + q) * 128 + cc]);
  }
}

// ---- VT = d * (X @ Wcat) (transposed store) ----
__global__ __launch_bounds__(256) void k_gemm_xw(const unsigned short* __restrict__ XB,
                                                 const unsigned short* __restrict__ WT,
                                                 const float* __restrict__ dvec,
                                                 unsigned short* __restrict__ VT) {
  __shared__ unsigned short lA[2][2048], lB[2][4096];
  const int mt = blockIdx.x, ct = blockIdx.y, tid = threadIdx.x;
  f32x4 acc[4][2];
  gemm_core64(XB + mt * 64 * NF, NF, WT + ct * 128 * NF, NF, NF / 32,
              lA[0], lA[1], lB[0], lB[1], tid, acc);
  const int lane = tid & 63, wave = tid >> 6;
  const int l15 = lane & 15, l4 = (lane >> 4) * 4;
#pragma unroll
  for (int i = 0; i < 4; ++i) {
    const int gr0 = mt * 64 + i * 16 + l4;
    const int b = gr0 >> 11, n0 = gr0 & 2047;
    const f32x4 dv = *(const f32x4*)(dvec + gr0);
#pragma unroll
    for (int j = 0; j < 2; ++j) {
      const int gc = ct * 128 + wave * 32 + j * 16 + l15;
      u16x4 pk;
#pragma unroll
      for (int r = 0; r < 4; ++r) pk[r] = f2b(acc[i][j][r] * dv[r]);
      *(u16x4*)(VT + (((size_t)(b * NC2 + gc)) << 11) + n0) = pk;
    }
  }
}

// ---- U = (A@V + V)*d;  ct=0 -> Z_T; ct=1 -> fused softmax S + S_T + entropy.
// XCD-pinned: pid&7 = XCD = batch; slot pairs ct adjacent (A-panel L2 reuse),
// keeps the batch's two 512KB V-panels L2-resident across all 32 mt re-reads.
__global__ __launch_bounds__(256) void k_gemm_nv(const unsigned short* __restrict__ AB,
                                                 const unsigned short* __restrict__ VT,
                                                 const float* __restrict__ dvec,
                                                 unsigned short* __restrict__ YT,
                                                 float* __restrict__ out,
                                                 float* __restrict__ entv) {
  __shared__ unsigned short lA[2][2048], lB[2][4096];
  const int pid = blockIdx.x, tid = threadIdx.x;
  const int b = pid & 7, slot = pid >> 3;
  const int mt = slot >> 1, ct = slot & 1;
  const unsigned short* Aop = AB + ((size_t)b << 22) + (size_t)mt * 64 * NN;
  const unsigned short* Bop = VT + (((size_t)(b * NC2 + ct * 128)) << 11);
  f32x4 acc[4][2];
  gemm_core64(Aop, NN, Bop, NN, NN / 32, lA[0], lA[1], lB[0], lB[1], tid, acc);
  const int lane = tid & 63, wave = tid >> 6;
  const int l15 = lane & 15, l4g = lane >> 4, l4 = l4g * 4;
  f32x4 dv[4];
#pragma unroll
  for (int i = 0; i < 4; ++i)
    dv[i] = *(const f32x4*)(dvec + (b << 11) + mt * 64 + i * 16 + l4);
#pragma unroll
  for (int i = 0; i < 4; ++i) {
    const int n0 = mt * 64 + i * 16 + l4;
#pragma unroll
    for (int j = 0; j < 2; ++j) {
      const int c = ct * 128 + wave * 32 + j * 16 + l15;
      const u16x4 vv = *(const u16x4*)(VT + (((size_t)(b * NC2 + c)) << 11) + n0);
#pragma unroll
      for (int r = 0; r < 4; ++r)
        acc[i][j][r] = (acc[i][j][r] + b2f(vv[r])) * dv[i][r];
    }
  }
  if (ct == 0) {
#pragma unroll
    for (int i = 0; i < 4; ++i) {
      const int n0 = mt * 64 + i * 16 + l4;
#pragma unroll
      for (int j = 0; j < 2; ++j) {
        const int c = wave * 32 + j * 16 + l15;
        u16x4 pk;
#pragma unroll
        for (int r = 0; r < 4; ++r) pk[r] = f2b(acc[i][j][r]);
        *(u16x4*)(YT + (((size_t)(b * 384 + c)) << 11) + n0) = pk;
      }
    }
    return;                                        // ct block-uniform
  }
  // fused softmax over k=128 (cols: 4 waves x 2 j x 16 l15)
  float* mbuf = (float*)lA;                        // [4][64]
  float* sbuf = mbuf + 256;
  float* tbuf = mbuf + 512;
  float* ebuf = mbuf + 768;
  float rm[4][4], rs[4][4], rt[4][4];
#pragma unroll
  for (int i = 0; i < 4; ++i)
#pragma unroll
    for (int r = 0; r < 4; ++r) {
      float m = fmaxf(acc[i][0][r], acc[i][1][r]);
#pragma unroll
      for (int off = 1; off < 16; off <<= 1) m = fmaxf(m, __shfl_xor(m, off));
      if (l15 == 0) mbuf[wave * 64 + i * 16 + l4 + r] = m;
    }
  __syncthreads();
#pragma unroll
  for (int i = 0; i < 4; ++i)
#pragma unroll
    for (int r = 0; r < 4; ++r) {
      const int row = i * 16 + l4 + r;
      rm[i][r] = fmaxf(fmaxf(mbuf[row], mbuf[64 + row]),
                       fmaxf(mbuf[128 + row], mbuf[192 + row]));
      rs[i][r] = 0.f; rt[i][r] = 0.f;
    }
#pragma unroll
  for (int i = 0; i < 4; ++i)
#pragma unroll
    for (int j = 0; j < 2; ++j)
#pragma unroll
      for (int r = 0; r < 4; ++r) {
        const float xm = acc[i][j][r] - rm[i][r];
        const float e = __expf(xm);
        acc[i][j][r] = e;
        rs[i][r] += e;
        rt[i][r] += xm * e;
      }
#pragma unroll
  for (int i = 0; i < 4; ++i)
#pragma unroll
    for (int r = 0; r < 4; ++r) {
      float s = rs[i][r], t = rt[i][r];
#pragma unroll
      for (int off = 1; off < 16; off <<= 1) {
        s += __shfl_xor(s, off); t += __shfl_xor(t, off);
      }
      if (l15 == 0) {
        sbuf[wave * 64 + i * 16 + l4 + r] = s;
        tbuf[wave * 64 + i * 16 + l4 + r] = t;
      }
    }
  __syncthreads();
  float ent = 0.f;
#pragma unroll
  for (int i = 0; i < 4; ++i)
#pragma unroll
    for (int r = 0; r < 4; ++r) {
      const int row = i * 16 + l4 + r;
      const float s = sbuf[row] + sbuf[64 + row] + sbuf[128 + row] + sbuf[192 + row];
      const float t = tbuf[row] + tbuf[64 + row] + tbuf[128 + row] + tbuf[192 + row];
      const float inv = 1.f / s;
      rs[i][r] = inv;
      ent += __logf(s) - t * inv;
    }
#pragma unroll
  for (int i = 0; i < 4; ++i) {
    const int n0 = mt * 64 + i * 16 + l4;
#pragma unroll
    for (int j = 0; j < 2; ++j) {
      const int c = wave * 32 + j * 16 + l15;
      u16x4 pk;
#pragma unroll
      for (int r = 0; r < 4; ++r) {
        const float sv = acc[i][j][r] * rs[i][r];
        pk[r] = f2b(sv);
        out[OUT_S0 + (((size_t)((b << 11) + n0 + r)) << 7) + c] = sv;
      }
      *(u16x4*)(YT + (((size_t)(b * 384 + 256 + c)) << 11) + n0) = pk;
    }
  }
  if (wave == 0 && l15 == 0) ebuf[l4g] = ent;
  __syncthreads();
  if (tid == 0)
    entv[b * 32 + mt] = ebuf[0] + ebuf[1] + ebuf[2] + ebuf[3];
}

// ---- AS_T = (A @ S)^T -> YT rows 128..255 (XCD-pinned: batch = pid&7) ----
__global__ __launch_bounds__(256) void k_gemm_as(const unsigned short* __restrict__ AB,
                                                 unsigned short* __restrict__ YT) {
  __shared__ unsigned short lA[2][2048], lB[2][4096];
  const int pid = blockIdx.x, tid = threadIdx.x;
  const int b = pid & 7, mt = pid >> 3;
  f32x4 acc[4][2];
  gemm_core64(AB + ((size_t)b << 22) + (size_t)mt * 64 * NN, NN,
              YT + (((size_t)(b * 384 + 256)) << 11), NN, NN / 32,
              lA[0], lA[1], lB[0], lB[1], tid, acc);
  const int lane = tid & 63, wave = tid >> 6;
  const int l15 = lane & 15, l4 = (lane >> 4) * 4;
#pragma unroll
  for (int i = 0; i < 4; ++i) {
    const int n0 = mt * 64 + i * 16 + l4;
#pragma unroll
    for (int j = 0; j < 2; ++j) {
      const int c = wave * 32 + j * 16 + l15;
      u16x4 pk;
#pragma unroll
      for (int r = 0; r < 4; ++r) pk[r] = f2b(acc[i][j][r]);
      *(u16x4*)(YT + (((size_t)(b * 384 + 128 + c)) << 11) + n0) = pk;
    }
  }
}

// ---- P = S^T @ [Z|AS|S], split-K=16 -> fp32 partials (XCD-pinned by batch) ----
__global__ __launch_bounds__(256) void k_gemm_p(const unsigned short* __restrict__ YT,
                                                float* __restrict__ Pp) {
  __shared__ unsigned short lA[2][4096], lB[2][4096];
  const int pid = blockIdx.x, tid = threadIdx.x;
  const int b = pid & 7, slot = pid >> 3;          // slot 0..47
  const int ct = slot % 3, sk = slot / 3;
  f32x4 acc[4][4];
  gemm_core128(YT + (((size_t)(b * 384 + 256)) << 11) + sk * 128, NN,
               YT + (((size_t)(b * 384 + ct * 128)) << 11) + sk * 128, NN, 4,
               lA[0], lA[1], lB[0], lB[1], tid, acc);
  const int lane = tid & 63, wave = tid >> 6;
  const int wr = wave >> 1, wc = wave & 1, l15 = lane & 15, l4 = (lane >> 4) * 4;
  float* dst = Pp + ((size_t)(sk * NB + b)) * 128 * 384;
#pragma unroll
  for (int i = 0; i < 4; ++i) {
    const int p0 = wr * 64 + i * 16 + l4;
#pragma unroll
    for (int j = 0; j < 4; ++j) {
      const int gc = ct * 128 + wc * 64 + j * 16 + l15;
#pragma unroll
      for (int r = 0; r < 4; ++r) dst[(p0 + r) * 384 + gc] = acc[i][j][r];
    }
  }
}

// ---- reduce split-K; write X_pooled/A_pooled; tr/g2 partials ----
__global__ __launch_bounds__(256) void k_reduce_p(const float* __restrict__ Pp,
                                                  float* __restrict__ trp,
                                                  float* __restrict__ g2p,
                                                  float* __restrict__ out) {
  const int chunk = blockIdx.x, b = blockIdx.y, tid = threadIdx.x;
  const int e = chunk * 256 + tid;
  const int p = e / 384, c = e - p * 384;
  float s = 0.f;
#pragma unroll
  for (int sk = 0; sk < NSK; ++sk)
    s += Pp[((size_t)(sk * NB + b)) * (128 * 384) + e];
  float tr = 0.f, g2 = 0.f;
  if (c < 128) {
    out[OUT_X0 + ((size_t)(b * 128 + p)) * 128 + c] = s;
  } else if (c < 256) {
    out[OUT_A0 + ((size_t)(b * 128 + p)) * 128 + (c - 128)] = s;
    if (c - 128 == p) tr = s;
  } else {
    g2 = s * s;
  }
  __shared__ float rb[512];
  rb[tid] = tr; rb[256 + tid] = g2;
  __syncthreads();
  for (int o = 128; o; o >>= 1) {
    if (tid < o) { rb[tid] += rb[tid + o]; rb[256 + tid] += rb[256 + tid + o]; }
    __syncthreads();
  }
  if (tid == 0) { trp[b * 192 + chunk] = rb[0]; g2p[b * 192 + chunk] = rb[256]; }
}

__global__ __launch_bounds__(256) void k_lp(const float* __restrict__ rsum,
                                            const float* __restrict__ trp,
                                            const float* __restrict__ g2p,
                                            float* __restrict__ lpv) {
  const int b = blockIdx.x, tid = threadIdx.x;
  float nz = 0.f;
#pragma unroll
  for (int i = 0; i < 8; ++i) nz += rsum[(b << 11) + i * 256 + tid];
  float tr = (tid < 192) ? trp[b * 192 + tid] : 0.f;
  float g2 = (tid < 192) ? g2p[b * 192 + tid] : 0.f;
  __shared__ float rb[768];
  rb[tid] = nz; rb[256 + tid] = tr; rb[512 + tid] = g2;
  __syncthreads();
  for (int o = 128; o; o >>= 1) {
    if (tid < o) {
      rb[tid] += rb[tid + o];
      rb[256 + tid] += rb[256 + tid + o];
      rb[512 + tid] += rb[512 + tid + o];
    }
    __syncthreads();
  }
  if (tid == 0)
    lpv[b] = sqrtf(fmaxf(rb[0] - 2.f * rb[256] + rb[512], 0.f));
}

__global__ __launch_bounds__(256) void k_losses(const float* __restrict__ entv,
                                                const float* __restrict__ lpv,
                                                float* __restrict__ out) {
  const int tid = threadIdx.x;
  __shared__ float rb[256];
  rb[tid] = entv[tid];
  __syncthreads();
  for (int o = 128; o; o >>= 1) {
    if (tid < o) rb[tid] += rb[tid + o];
    __syncthreads();
  }
  if (tid == 0) {
    float lp = 0.f;
#pragma unroll
    for (int b = 0; b < 8; ++b) lp += lpv[b];
    out[OUT_LP] = 0.125f * lp;
    out[OUT_ENT] = rb[0] * (1.f / (NB * NN));
  }
}

extern "C" void kernel_launch(void* const* d_in, const int* in_sizes, int n_in,
                              void* d_out, int out_size, void* d_ws, size_t ws_size,
                              hipStream_t stream) {
  const float* X     = (const float*)d_in[0];
  const float* A     = (const float*)d_in[1];
  const float* Wemb  = (const float*)d_in[2];
  const float* Wpool = (const float*)d_in[3];
  float* out = (float*)d_out;

  char* ws = (char*)d_ws;
  size_t o = 0;
  unsigned short* AB = (unsigned short*)(ws + o); o += (size_t)NB * NN * NN * 2;
  unsigned short* XB = (unsigned short*)(ws + o); o += (size_t)NB * NN * NF * 2;
  unsigned short* WT = (unsigned short*)(ws + o); o += (size_t)NC2 * NF * 2;
  unsigned short* VT = (unsigned short*)(ws + o); o += (size_t)NB * NC2 * NN * 2;
  unsigned short* YT = (unsigned short*)(ws + o); o += (size_t)NB * 384 * NN * 2;
  float* Pp  = (float*)(ws + o); o += (size_t)NSK * NB * 128 * 384 * 4;
  float* dvec = (float*)(ws + o); o += (size_t)NB * NN * 4;
  float* rsum = (float*)(ws + o); o += (size_t)NB * NN * 4;
  float* trp  = (float*)(ws + o); o += (size_t)NB * 192 * 4;
  float* g2p  = (float*)(ws + o); o += (size_t)NB * 192 * 4;
  float* entv = (float*)(ws + o); o += 256 * 4;
  float* lpv  = (float*)(ws + o); o += NB * 4;

  k_prep    <<<dim3(4624), 256, 0, stream>>>(A, X, Wemb, Wpool, AB, XB, WT, dvec, rsum);
  k_gemm_xw <<<dim3(NB * NN / 64, 2), 256, 0, stream>>>(XB, WT, dvec, VT);
  k_gemm_nv <<<dim3(512), 256, 0, stream>>>(AB, VT, dvec, YT, out, entv);
  k_gemm_as <<<dim3(256), 256, 0, stream>>>(AB, YT);
  k_gemm_p  <<<dim3(384), 256, 0, stream>>>(YT, Pp);
  k_reduce_p<<<dim3(192, NB), 256, 0, stream>>>(Pp, trp, g2p, out);
  k_lp      <<<dim3(NB), 256, 0, stream>>>(rsum, trp, g2p, lpv);
  k_losses  <<<1, 256, 0, stream>>>(entv, lpv, out);
}